// Round 2
// baseline (5077.402 us; speedup 1.0000x reference)
//
#include <hip/hip_runtime.h>
#include <hip/hip_bf16.h>
#include <math.h>

#define B_ 2
#define T_ 2048
#define C_ 1024
#define H_ 16
#define D_ 64
#define M_ (B_ * T_)   // 4096

// ---------------------------------------------------------------------------
// GEMM: out[M,N] = A[M,K] @ W[K,N] + bias[N]   (all fp32)
// mode 0: write row-major [M,N]
// mode 1: scatter to [B,H,T,D] (QKV heads layout)
// 64x64 block tile, K-tile 16, 256 threads, 4x4 micro-tile.
// ---------------------------------------------------------------------------
__global__ __launch_bounds__(256) void gemm_bias(
    const float* __restrict__ A, const float* __restrict__ W,
    const float* __restrict__ bias, float* __restrict__ out,
    int M, int N, int K, int mode)
{
    __shared__ float As[16][65];
    __shared__ float Bs[16][65];
    const int tid = threadIdx.x;
    const int m0 = blockIdx.y * 64;
    const int n0 = blockIdx.x * 64;

    const int ar = tid >> 2;          // 0..63 : A row within tile
    const int ak = (tid & 3) * 4;     // 0,4,8,12 : A k within tile
    const int wk = tid >> 4;          // 0..15 : W k within tile
    const int wn = (tid & 15) * 4;    // 0..60 : W col within tile

    const int tm = (tid >> 4) * 4;    // micro-tile row base
    const int tn = (tid & 15) * 4;    // micro-tile col base

    float acc[4][4] = {{0.f}};

    for (int k0 = 0; k0 < K; k0 += 16) {
        const float4 a4 = *reinterpret_cast<const float4*>(A + (size_t)(m0 + ar) * K + (k0 + ak));
        const float4 w4 = *reinterpret_cast<const float4*>(W + (size_t)(k0 + wk) * N + (n0 + wn));
        As[ak + 0][ar] = a4.x; As[ak + 1][ar] = a4.y;
        As[ak + 2][ar] = a4.z; As[ak + 3][ar] = a4.w;
        Bs[wk][wn + 0] = w4.x; Bs[wk][wn + 1] = w4.y;
        Bs[wk][wn + 2] = w4.z; Bs[wk][wn + 3] = w4.w;
        __syncthreads();
        #pragma unroll
        for (int kk = 0; kk < 16; ++kk) {
            float a0 = As[kk][tm + 0], a1 = As[kk][tm + 1];
            float a2 = As[kk][tm + 2], a3 = As[kk][tm + 3];
            float b0 = Bs[kk][tn + 0], b1 = Bs[kk][tn + 1];
            float b2 = Bs[kk][tn + 2], b3 = Bs[kk][tn + 3];
            acc[0][0] += a0 * b0; acc[0][1] += a0 * b1; acc[0][2] += a0 * b2; acc[0][3] += a0 * b3;
            acc[1][0] += a1 * b0; acc[1][1] += a1 * b1; acc[1][2] += a1 * b2; acc[1][3] += a1 * b3;
            acc[2][0] += a2 * b0; acc[2][1] += a2 * b1; acc[2][2] += a2 * b2; acc[2][3] += a2 * b3;
            acc[3][0] += a3 * b0; acc[3][1] += a3 * b1; acc[3][2] += a3 * b2; acc[3][3] += a3 * b3;
        }
        __syncthreads();
    }

    #pragma unroll
    for (int x = 0; x < 4; ++x) {
        const int m = m0 + tm + x;
        #pragma unroll
        for (int y = 0; y < 4; ++y) {
            const int n = n0 + tn + y;
            float val = acc[x][y] + bias[n];
            if (mode == 0) {
                out[(size_t)m * N + n] = val;
            } else {
                const int b = m / T_, t = m % T_;
                const int h = n >> 6, d = n & 63;
                out[(((size_t)b * H_ + h) * T_ + t) * D_ + d] = val;
            }
        }
    }
}

// ---------------------------------------------------------------------------
// Rotary embedding in-place on [B,H,T,D] fp32.
// Pair (d, d^32-partner) lives inside one 64-element row; a 256-thread block
// covers 4 complete rows, so read-all / barrier / write-all is race-free.
// ---------------------------------------------------------------------------
__global__ __launch_bounds__(256) void rotary_kernel(float* Q)
{
    const int idx = blockIdx.x * 256 + threadIdx.x;   // over B*H*T*D
    const int d = idx & 63;
    const int row = idx >> 6;        // b*H*T + h*T + t
    const int t = row & (T_ - 1);
    const int j = d & 31;
    // inv_freq = 10000^{-j/32}
    const float inv = expf(-(float)j * (9.210340371976184f / 32.0f));
    const float ang = (float)t * inv;
    const float c = cosf(ang), s = sinf(ang);
    const float v = Q[idx];
    const float partner = Q[(d < 32) ? (idx + 32) : (idx - 32)];
    const float r = (d < 32) ? (v * c - partner * s) : (v * c + partner * s);
    __syncthreads();
    Q[idx] = r;
}

// ---------------------------------------------------------------------------
// Attention: one block per (query row i, b*H+h). Exact two-pass softmax with
// scores materialized in LDS. score = (q.k + bias[bucket,h]) / 8, causal.
// Writes y in [B,T,C] layout for the final projection.
// ---------------------------------------------------------------------------
__global__ __launch_bounds__(256) void attn_kernel(
    const float* __restrict__ Q, const float* __restrict__ Kt,
    const float* __restrict__ V, const float* __restrict__ table,
    float* __restrict__ Y)
{
    __shared__ float qs[64];
    __shared__ float sc[T_];
    __shared__ float red[256];
    __shared__ float pv[4][64];

    const int i = blockIdx.x;
    const int bh = blockIdx.y;              // b*H + h
    const int h = bh & (H_ - 1);
    const int tid = threadIdx.x;
    const size_t base = (size_t)bh * T_ * D_;

    if (tid < 64) qs[tid] = Q[base + (size_t)i * D_ + tid];
    __syncthreads();

    const float scale = 0.125f;                        // 1/sqrt(64)
    const float inv_log8_x16 = 16.0f / 2.0794415416798357f;  // 16/log(128/16)

    float lmax = -INFINITY;
    for (int jj = tid; jj <= i; jj += 256) {
        const float* kr = Kt + base + (size_t)jj * D_;
        float dot = 0.f;
        #pragma unroll
        for (int d2 = 0; d2 < 64; ++d2) dot += qs[d2] * kr[d2];
        const int n = i - jj;
        int bucket;
        if (n < 16) {
            bucket = n;
        } else {
            int vb = 16 + (int)(logf((float)n * 0.0625f) * inv_log8_x16);
            bucket = vb < 31 ? vb : 31;
        }
        const float bias = table[bucket * H_ + h];
        const float s = (dot + bias) * scale;
        sc[jj] = s;
        lmax = fmaxf(lmax, s);
    }
    red[tid] = lmax; __syncthreads();
    for (int s = 128; s > 0; s >>= 1) {
        if (tid < s) red[tid] = fmaxf(red[tid], red[tid + s]);
        __syncthreads();
    }
    const float mx = red[0];
    __syncthreads();

    float lsum = 0.f;
    for (int jj = tid; jj <= i; jj += 256) {
        const float p = expf(sc[jj] - mx);
        sc[jj] = p;
        lsum += p;
    }
    red[tid] = lsum; __syncthreads();
    for (int s = 128; s > 0; s >>= 1) {
        if (tid < s) red[tid] += red[tid + s];
        __syncthreads();
    }
    const float denom = red[0];
    __syncthreads();

    const int g = tid >> 6, d = tid & 63;
    float acc = 0.f;
    for (int jj = g; jj <= i; jj += 4)
        acc += sc[jj] * V[base + (size_t)jj * D_ + d];
    pv[g][d] = acc;
    __syncthreads();

    if (tid < 64) {
        const float o = (pv[0][d] + pv[1][d] + pv[2][d] + pv[3][d]) / denom;
        const int b = bh >> 4;
        Y[((size_t)b * T_ + i) * C_ + h * D_ + d] = o;
    }
}

// ---------------------------------------------------------------------------
extern "C" void kernel_launch(void* const* d_in, const int* in_sizes, int n_in,
                              void* d_out, int out_size, void* d_ws, size_t ws_size,
                              hipStream_t stream)
{
    const float* x   = (const float*)d_in[0];
    const float* Wq  = (const float*)d_in[1];
    const float* bq  = (const float*)d_in[2];
    const float* Wk  = (const float*)d_in[3];
    const float* bk  = (const float*)d_in[4];
    const float* Wv  = (const float*)d_in[5];
    const float* bv  = (const float*)d_in[6];
    const float* Wp  = (const float*)d_in[7];
    const float* bp  = (const float*)d_in[8];
    const float* tbl = (const float*)d_in[9];
    float* out = (float*)d_out;

    const size_t n1 = (size_t)B_ * H_ * T_ * D_;   // 4,194,304 elems
    float* Qb = (float*)d_ws;
    float* Kb = Qb + n1;
    float* Vb = Kb + n1;
    float* Yb = Vb + n1;                           // total 64 MB of ws

    const dim3 gemm_grid(C_ / 64, M_ / 64);        // (16, 64)
    const dim3 blk(256);

    gemm_bias<<<gemm_grid, blk, 0, stream>>>(x, Wq, bq, Qb, M_, C_, C_, 1);
    gemm_bias<<<gemm_grid, blk, 0, stream>>>(x, Wk, bk, Kb, M_, C_, C_, 1);
    gemm_bias<<<gemm_grid, blk, 0, stream>>>(x, Wv, bv, Vb, M_, C_, C_, 1);

    const int rot_blocks = (int)(n1 / 256);        // 16384
    rotary_kernel<<<rot_blocks, blk, 0, stream>>>(Qb);
    rotary_kernel<<<rot_blocks, blk, 0, stream>>>(Kb);

    attn_kernel<<<dim3(T_, B_ * H_), blk, 0, stream>>>(Qb, Kb, Vb, tbl, Yb);

    gemm_bias<<<gemm_grid, blk, 0, stream>>>(Yb, Wp, bp, out, M_, C_, C_, 0);
}

// Round 3
// 981.438 us; speedup vs baseline: 5.1734x; 5.1734x over previous
//
#include <hip/hip_runtime.h>
#include <hip/hip_bf16.h>
#include <math.h>

#define B_ 2
#define T_ 2048
#define C_ 1024
#define H_ 16
#define D_ 64
#define M_ (B_ * T_)   // 4096

typedef short bf16x8 __attribute__((ext_vector_type(8)));
typedef float f32x4  __attribute__((ext_vector_type(4)));

__device__ __forceinline__ float u2f(unsigned short u) {
    union { unsigned int i; float f; } v; v.i = ((unsigned int)u) << 16; return v.f;
}
__device__ __forceinline__ unsigned short f2b(float f) {
    __hip_bfloat16 h = __float2bfloat16(f);
    return *reinterpret_cast<unsigned short*>(&h);
}

// ---------------------------------------------------------------------------
// GEMM: out[M,N] = A[M,K] @ W[K,N] + bias[N]   (A,W,bias fp32, fp32 accumulate)
// mode 0: write fp32 row-major [M,N] to outf
// mode 1: write bf16 scattered to [B,H,T,D] heads layout to outb
// 64x64 block tile, K-tile 16, 256 threads, 4x4 micro-tile.
// ---------------------------------------------------------------------------
__global__ __launch_bounds__(256) void gemm_bias(
    const float* __restrict__ A, const float* __restrict__ W,
    const float* __restrict__ bias, float* __restrict__ outf,
    unsigned short* __restrict__ outb, int M, int N, int K, int mode)
{
    __shared__ float As[16][65];
    __shared__ float Bs[16][65];
    const int tid = threadIdx.x;
    const int m0 = blockIdx.y * 64;
    const int n0 = blockIdx.x * 64;

    const int ar = tid >> 2;          // 0..63 : A row within tile
    const int ak = (tid & 3) * 4;     // 0,4,8,12 : A k within tile
    const int wk = tid >> 4;          // 0..15 : W k within tile
    const int wn = (tid & 15) * 4;    // 0..60 : W col within tile

    const int tm = (tid >> 4) * 4;    // micro-tile row base
    const int tn = (tid & 15) * 4;    // micro-tile col base

    float acc[4][4] = {{0.f}};

    for (int k0 = 0; k0 < K; k0 += 16) {
        const float4 a4 = *reinterpret_cast<const float4*>(A + (size_t)(m0 + ar) * K + (k0 + ak));
        const float4 w4 = *reinterpret_cast<const float4*>(W + (size_t)(k0 + wk) * N + (n0 + wn));
        As[ak + 0][ar] = a4.x; As[ak + 1][ar] = a4.y;
        As[ak + 2][ar] = a4.z; As[ak + 3][ar] = a4.w;
        Bs[wk][wn + 0] = w4.x; Bs[wk][wn + 1] = w4.y;
        Bs[wk][wn + 2] = w4.z; Bs[wk][wn + 3] = w4.w;
        __syncthreads();
        #pragma unroll
        for (int kk = 0; kk < 16; ++kk) {
            float a0 = As[kk][tm + 0], a1 = As[kk][tm + 1];
            float a2 = As[kk][tm + 2], a3 = As[kk][tm + 3];
            float b0 = Bs[kk][tn + 0], b1 = Bs[kk][tn + 1];
            float b2 = Bs[kk][tn + 2], b3 = Bs[kk][tn + 3];
            acc[0][0] += a0 * b0; acc[0][1] += a0 * b1; acc[0][2] += a0 * b2; acc[0][3] += a0 * b3;
            acc[1][0] += a1 * b0; acc[1][1] += a1 * b1; acc[1][2] += a1 * b2; acc[1][3] += a1 * b3;
            acc[2][0] += a2 * b0; acc[2][1] += a2 * b1; acc[2][2] += a2 * b2; acc[2][3] += a2 * b3;
            acc[3][0] += a3 * b0; acc[3][1] += a3 * b1; acc[3][2] += a3 * b2; acc[3][3] += a3 * b3;
        }
        __syncthreads();
    }

    #pragma unroll
    for (int x = 0; x < 4; ++x) {
        const int m = m0 + tm + x;
        #pragma unroll
        for (int y = 0; y < 4; ++y) {
            const int n = n0 + tn + y;
            float val = acc[x][y] + bias[n];
            if (mode == 0) {
                outf[(size_t)m * N + n] = val;
            } else {
                const int b = m / T_, t = m % T_;
                const int h = n >> 6, d = n & 63;
                outb[(((size_t)b * H_ + h) * T_ + t) * D_ + d] = f2b(val);
            }
        }
    }
}

// ---------------------------------------------------------------------------
// Rotary embedding in-place on [B,H,T,D] bf16.
// 256-thread block covers 4 complete 64-wide rows: read-all / barrier / write.
// ---------------------------------------------------------------------------
__global__ __launch_bounds__(256) void rotary_kernel(unsigned short* Q)
{
    const int idx = blockIdx.x * 256 + threadIdx.x;   // over B*H*T*D
    const int d = idx & 63;
    const int row = idx >> 6;        // b*H*T + h*T + t
    const int t = row & (T_ - 1);
    const int j = d & 31;
    const float inv = expf(-(float)j * (9.210340371976184f / 32.0f));  // 10000^{-j/32}
    const float ang = (float)t * inv;
    const float c = cosf(ang), s = sinf(ang);
    const float v = u2f(Q[idx]);
    const float partner = u2f(Q[(d < 32) ? (idx + 32) : (idx - 32)]);
    const float r = (d < 32) ? (v * c - partner * s) : (v * c + partner * s);
    __syncthreads();
    Q[idx] = f2b(r);
}

// ---------------------------------------------------------------------------
// Transpose V [BH, T, D] -> Vt [BH, D, T]  (bf16), 64x64 tiles.
// ---------------------------------------------------------------------------
__global__ __launch_bounds__(256) void transpose_v(
    const unsigned short* __restrict__ V, unsigned short* __restrict__ Vt)
{
    __shared__ __align__(16) unsigned short tile[64][72];
    const int t0 = blockIdx.x * 64;
    const int bh = blockIdx.y;
    const int tid = threadIdx.x;

    #pragma unroll
    for (int it = 0; it < 2; ++it) {
        const int idx = tid + it * 256;
        const int r = idx >> 3, ch = (idx & 7) * 8;
        *reinterpret_cast<bf16x8*>(&tile[r][ch]) =
            *reinterpret_cast<const bf16x8*>(V + ((size_t)bh * T_ + t0 + r) * D_ + ch);
    }
    __syncthreads();
    #pragma unroll
    for (int it = 0; it < 2; ++it) {
        const int idx = tid + it * 256;
        const int d = idx >> 3, ch = (idx & 7) * 8;
        unsigned short tmp[8];
        #pragma unroll
        for (int e = 0; e < 8; ++e) tmp[e] = tile[ch + e][d];
        *reinterpret_cast<bf16x8*>(Vt + ((size_t)bh * D_ + d) * T_ + t0 + ch) =
            *reinterpret_cast<const bf16x8*>(tmp);
    }
}

// ---------------------------------------------------------------------------
// Flash attention with MFMA bf16 16x16x32.
// Block = 4 waves, one 64-row Q-tile of one (b,h). K-tiles of 64 up to diag.
// Q frags in registers; K, V^T tiles staged in LDS (+8 pad); P round-trips
// through per-wave LDS region (C-layout -> A-layout). Online softmax in regs.
// Layouts (HW-verified per docs): A[m=lane&15][k=quad*8+j],
// B[k=quad*8+j][n=lane&15], C/D[row=quad*4+reg][col=lane&15].
// ---------------------------------------------------------------------------
__global__ __launch_bounds__(256) void flash_attn(
    const unsigned short* __restrict__ Q, const unsigned short* __restrict__ K,
    const unsigned short* __restrict__ Vt, const float* __restrict__ table,
    float* __restrict__ Y)
{
    __shared__ __align__(16) unsigned short Ks[64][72];
    __shared__ __align__(16) unsigned short Vs[64][72];
    __shared__ __align__(16) unsigned short Ps[4][16][72];
    __shared__ float bias_h[32];

    const int qt = blockIdx.x;
    const int bh = blockIdx.y;
    const int h = bh & (H_ - 1), b = bh >> 4;
    const int tid = threadIdx.x;
    const int wid = tid >> 6, lane = tid & 63;
    const int l16 = lane & 15, quad = lane >> 4;

    if (tid < 32) bias_h[tid] = table[tid * H_ + h];

    const size_t base = (size_t)bh * T_ * D_;
    const int q0 = qt * 64;
    const int arow = q0 + wid * 16 + l16;            // A-frag row (global)
    const int crow = q0 + wid * 16 + quad * 4;       // C-layout row base (+reg)

    bf16x8 qf[2];
    qf[0] = *reinterpret_cast<const bf16x8*>(Q + base + (size_t)arow * D_ + quad * 8);
    qf[1] = *reinterpret_cast<const bf16x8*>(Q + base + (size_t)arow * D_ + 32 + quad * 8);

    f32x4 o[4];
    #pragma unroll
    for (int c = 0; c < 4; ++c) o[c] = (f32x4){0.f, 0.f, 0.f, 0.f};
    float m_r[4] = {-INFINITY, -INFINITY, -INFINITY, -INFINITY};
    float l_r[4] = {0.f, 0.f, 0.f, 0.f};

    for (int kt = 0; kt <= qt; ++kt) {
        const int j0 = kt * 64;
        __syncthreads();   // previous iteration's LDS reads done
        #pragma unroll
        for (int it = 0; it < 2; ++it) {
            const int idx = tid + it * 256;
            const int r = idx >> 3, ch = (idx & 7) * 8;
            *reinterpret_cast<bf16x8*>(&Ks[r][ch]) =
                *reinterpret_cast<const bf16x8*>(K + base + (size_t)(j0 + r) * D_ + ch);
            *reinterpret_cast<bf16x8*>(&Vs[r][ch]) =
                *reinterpret_cast<const bf16x8*>(Vt + ((size_t)bh * D_ + r) * T_ + j0 + ch);
        }
        __syncthreads();   // staging visible

        // ---- S = Q K^T (per wave: 16 rows x 64 cols) ----
        f32x4 sc[4];
        #pragma unroll
        for (int c = 0; c < 4; ++c) sc[c] = (f32x4){0.f, 0.f, 0.f, 0.f};
        #pragma unroll
        for (int c = 0; c < 4; ++c) {
            #pragma unroll
            for (int s = 0; s < 2; ++s) {
                bf16x8 kf = *reinterpret_cast<const bf16x8*>(&Ks[c * 16 + l16][s * 32 + quad * 8]);
                sc[c] = __builtin_amdgcn_mfma_f32_16x16x32_bf16(qf[s], kf, sc[c], 0, 0, 0);
            }
        }

        // ---- bias + causal mask, track row maxima ----
        float sv[4][4];
        float rmax[4] = {-INFINITY, -INFINITY, -INFINITY, -INFINITY};
        #pragma unroll
        for (int c = 0; c < 4; ++c) {
            const int jcol = j0 + c * 16 + l16;
            #pragma unroll
            for (int r = 0; r < 4; ++r) {
                const int n = (crow + r) - jcol;
                float s;
                if (n < 0) {
                    s = -INFINITY;
                } else {
                    int bucket;
                    if (n < 16) bucket = n;
                    else {
                        int vb = 16 + (int)(log2f((float)n * 0.0625f) * (16.0f / 3.0f));
                        bucket = vb < 31 ? vb : 31;
                    }
                    s = (sc[c][r] + bias_h[bucket]) * 0.125f;
                }
                sv[c][r] = s;
                rmax[r] = fmaxf(rmax[r], s);
            }
        }
        #pragma unroll
        for (int r = 0; r < 4; ++r) {
            #pragma unroll
            for (int off = 1; off < 16; off <<= 1)
                rmax[r] = fmaxf(rmax[r], __shfl_xor(rmax[r], off, 64));
        }

        // ---- online softmax update ----
        float alpha[4], rsum[4];
        #pragma unroll
        for (int r = 0; r < 4; ++r) {
            const float mn = fmaxf(m_r[r], rmax[r]);
            alpha[r] = expf(m_r[r] - mn);      // 0 on first tile (m=-inf)
            m_r[r] = mn;
            rsum[r] = 0.f;
        }
        #pragma unroll
        for (int c = 0; c < 4; ++c) {
            #pragma unroll
            for (int r = 0; r < 4; ++r) {
                const float p = expf(sv[c][r] - m_r[r]);   // masked -> 0
                rsum[r] += p;
                Ps[wid][quad * 4 + r][c * 16 + l16] = f2b(p);
            }
        }
        #pragma unroll
        for (int r = 0; r < 4; ++r) {
            #pragma unroll
            for (int off = 1; off < 16; off <<= 1)
                rsum[r] += __shfl_xor(rsum[r], off, 64);
            l_r[r] = l_r[r] * alpha[r] + rsum[r];
        }
        #pragma unroll
        for (int c = 0; c < 4; ++c) {
            #pragma unroll
            for (int r = 0; r < 4; ++r) o[c][r] *= alpha[r];
        }

        // ---- O += P V  (P from own-wave LDS region; wave-synchronous) ----
        #pragma unroll
        for (int s = 0; s < 2; ++s) {
            bf16x8 pf = *reinterpret_cast<const bf16x8*>(&Ps[wid][l16][s * 32 + quad * 8]);
            #pragma unroll
            for (int c = 0; c < 4; ++c) {
                bf16x8 vf = *reinterpret_cast<const bf16x8*>(&Vs[c * 16 + l16][s * 32 + quad * 8]);
                o[c] = __builtin_amdgcn_mfma_f32_16x16x32_bf16(pf, vf, o[c], 0, 0, 0);
            }
        }
    }

    // ---- epilogue: normalize and write Y [B,T,C] fp32 ----
    #pragma unroll
    for (int r = 0; r < 4; ++r) {
        const int i = crow + r;
        const float invl = 1.0f / l_r[r];
        #pragma unroll
        for (int c = 0; c < 4; ++c)
            Y[((size_t)b * T_ + i) * C_ + h * D_ + c * 16 + l16] = o[c][r] * invl;
    }
}

// ---------------------------------------------------------------------------
extern "C" void kernel_launch(void* const* d_in, const int* in_sizes, int n_in,
                              void* d_out, int out_size, void* d_ws, size_t ws_size,
                              hipStream_t stream)
{
    const float* x   = (const float*)d_in[0];
    const float* Wq  = (const float*)d_in[1];
    const float* bq  = (const float*)d_in[2];
    const float* Wk  = (const float*)d_in[3];
    const float* bk  = (const float*)d_in[4];
    const float* Wv  = (const float*)d_in[5];
    const float* bv  = (const float*)d_in[6];
    const float* Wp  = (const float*)d_in[7];
    const float* bp  = (const float*)d_in[8];
    const float* tbl = (const float*)d_in[9];
    float* out = (float*)d_out;

    const size_t n1 = (size_t)B_ * H_ * T_ * D_;   // 4,194,304 elems
    unsigned short* Qb  = (unsigned short*)d_ws;
    unsigned short* Kb  = Qb + n1;
    unsigned short* Vb  = Kb + n1;
    unsigned short* Vtb = Vb + n1;
    float* Yb = (float*)(Vtb + n1);                // 33.5 MB + 16.8 MB total

    const dim3 gemm_grid(C_ / 64, M_ / 64);        // (16, 64)
    const dim3 blk(256);

    gemm_bias<<<gemm_grid, blk, 0, stream>>>(x, Wq, bq, nullptr, Qb, M_, C_, C_, 1);
    gemm_bias<<<gemm_grid, blk, 0, stream>>>(x, Wk, bk, nullptr, Kb, M_, C_, C_, 1);
    gemm_bias<<<gemm_grid, blk, 0, stream>>>(x, Wv, bv, nullptr, Vb, M_, C_, C_, 1);

    const int rot_blocks = (int)(n1 / 256);        // 16384
    rotary_kernel<<<rot_blocks, blk, 0, stream>>>(Qb);
    rotary_kernel<<<rot_blocks, blk, 0, stream>>>(Kb);

    transpose_v<<<dim3(T_ / 64, B_ * H_), blk, 0, stream>>>(Vb, Vtb);

    flash_attn<<<dim3(T_ / 64, B_ * H_), blk, 0, stream>>>(Qb, Kb, Vtb, tbl, Yb);

    gemm_bias<<<gemm_grid, blk, 0, stream>>>(Yb, Wp, bp, out, nullptr, M_, C_, C_, 0);
}

// Round 4
// 365.478 us; speedup vs baseline: 13.8925x; 2.6854x over previous
//
#include <hip/hip_runtime.h>
#include <hip/hip_bf16.h>
#include <math.h>

#define B_ 2
#define T_ 2048
#define C_ 1024
#define H_ 16
#define D_ 64
#define M_ (B_ * T_)   // 4096
#define K_ 1024

typedef short bf16x8 __attribute__((ext_vector_type(8)));
typedef float f32x4  __attribute__((ext_vector_type(4)));
typedef unsigned int u32;

__device__ __forceinline__ float u2f(unsigned short u) {
    union { unsigned int i; float f; } v; v.i = ((unsigned int)u) << 16; return v.f;
}
__device__ __forceinline__ unsigned short f2b(float f) {
    __hip_bfloat16 h = __float2bfloat16(f);
    return *reinterpret_cast<unsigned short*>(&h);
}
__device__ __forceinline__ void load_lds16(const void* g, void* l) {
    __builtin_amdgcn_global_load_lds(
        (const __attribute__((address_space(1))) u32*)g,
        (__attribute__((address_space(3))) u32*)l, 16, 0, 0);
}

// ---------------------------------------------------------------------------
// convert x fp32 -> bf16 (8 elems/thread)
// ---------------------------------------------------------------------------
__global__ __launch_bounds__(256) void convert_x(
    const float* __restrict__ x, unsigned short* __restrict__ xb)
{
    const int idx = blockIdx.x * 256 + threadIdx.x;     // over 4M/8 chunks
    const float4 a = reinterpret_cast<const float4*>(x)[idx * 2];
    const float4 b = reinterpret_cast<const float4*>(x)[idx * 2 + 1];
    unsigned short t[8] = {f2b(a.x), f2b(a.y), f2b(a.z), f2b(a.w),
                           f2b(b.x), f2b(b.y), f2b(b.z), f2b(b.w)};
    reinterpret_cast<bf16x8*>(xb)[idx] = *reinterpret_cast<const bf16x8*>(t);
}

// ---------------------------------------------------------------------------
// convert + transpose W [K,N] fp32 -> Wt [N,K] bf16, 64x64 tiles, z picks W.
// ---------------------------------------------------------------------------
__global__ __launch_bounds__(256) void convert_w(
    const float* __restrict__ W0, const float* __restrict__ W1,
    const float* __restrict__ W2, const float* __restrict__ W3,
    unsigned short* __restrict__ T0, unsigned short* __restrict__ T1,
    unsigned short* __restrict__ T2, unsigned short* __restrict__ T3)
{
    __shared__ __align__(16) unsigned short tile[64][72];
    const int z = blockIdx.z;
    const float* W = z == 0 ? W0 : z == 1 ? W1 : z == 2 ? W2 : W3;
    unsigned short* Wt = z == 0 ? T0 : z == 1 ? T1 : z == 2 ? T2 : T3;
    const int k0 = blockIdx.x * 64, n0 = blockIdx.y * 64;
    const int tid = threadIdx.x;

    #pragma unroll
    for (int it = 0; it < 4; ++it) {
        const int idx = it * 256 + tid;
        const int r = idx >> 4, c = (idx & 15) * 4;
        const float4 w4 = *reinterpret_cast<const float4*>(W + (size_t)(k0 + r) * C_ + n0 + c);
        tile[r][c + 0] = f2b(w4.x); tile[r][c + 1] = f2b(w4.y);
        tile[r][c + 2] = f2b(w4.z); tile[r][c + 3] = f2b(w4.w);
    }
    __syncthreads();
    #pragma unroll
    for (int it = 0; it < 2; ++it) {
        const int idx = it * 256 + tid;
        const int nc = idx >> 3, kc = (idx & 7) * 8;
        unsigned short tmp[8];
        #pragma unroll
        for (int e = 0; e < 8; ++e) tmp[e] = tile[kc + e][nc];
        *reinterpret_cast<bf16x8*>(Wt + (size_t)(n0 + nc) * K_ + k0 + kc) =
            *reinterpret_cast<const bf16x8*>(tmp);
    }
}

// ---------------------------------------------------------------------------
// Precompute distance bias table: dtab[h][n] = tbl[bucket(n)*H + h], n=0..T-1
// ---------------------------------------------------------------------------
__global__ __launch_bounds__(256) void build_bias(
    const float* __restrict__ tbl, float* __restrict__ dtab)
{
    const int idx = blockIdx.x * 256 + threadIdx.x;   // 16*2048
    const int h = idx >> 11, n = idx & (T_ - 1);
    int bucket;
    if (n < 16) bucket = n;
    else {
        int vb = 16 + (int)(log2f((float)n * 0.0625f) * (16.0f / 3.0f));
        bucket = vb < 31 ? vb : 31;
    }
    dtab[idx] = tbl[bucket * H_ + h];
}

// ---------------------------------------------------------------------------
// MFMA GEMM core: out[M,N] = A[M,K] @ Bt[N,K]^T + bias  (bf16 in, fp32 acc)
// 128x128 tile, BK=32, 4 waves (2x2), each wave 64x64 = 4x4 frags 16x16x32.
// global_load_lds width-16 staging (LDS layout = lane order, no padding).
// mode 0: fp32 row-major to outf.  mode 1: bf16 scatter to [B,H,T,D] outb.
// ---------------------------------------------------------------------------
__device__ __forceinline__ void gemm_core(
    const unsigned short* __restrict__ A, const unsigned short* __restrict__ Bt,
    const float* __restrict__ bias, float* __restrict__ outf,
    unsigned short* __restrict__ outb, int mode)
{
    __shared__ __align__(16) unsigned short As[128 * 32];
    __shared__ __align__(16) unsigned short Bs[128 * 32];

    const int tid = threadIdx.x;
    const int wid = tid >> 6, lane = tid & 63;
    const int l16 = lane & 15, quad = lane >> 4;
    const int wm = wid >> 1, wn = wid & 1;
    const int m0 = blockIdx.y * 128, n0 = blockIdx.x * 128;

    f32x4 acc[4][4];
    #pragma unroll
    for (int i = 0; i < 4; ++i)
        #pragma unroll
        for (int j = 0; j < 4; ++j) acc[i][j] = (f32x4){0.f, 0.f, 0.f, 0.f};

    char* AsB = (char*)As;
    char* BsB = (char*)Bs;

    for (int k0 = 0; k0 < K_; k0 += 32) {
        __syncthreads();   // prior frag reads complete before restage
        #pragma unroll
        for (int it = 0; it < 2; ++it) {
            const int idx = it * 256 + tid;
            const int row = idx >> 2, ch = (idx & 3) * 8;
            const int ldso = it * 4096 + wid * 1024;       // wave-uniform
            load_lds16(A + (size_t)(m0 + row) * K_ + k0 + ch, AsB + ldso);
            load_lds16(Bt + (size_t)(n0 + row) * K_ + k0 + ch, BsB + ldso);
        }
        __syncthreads();   // drains vmcnt(0)

        bf16x8 af[4], bf[4];
        #pragma unroll
        for (int i = 0; i < 4; ++i) {
            af[i] = *reinterpret_cast<const bf16x8*>(&As[(wm * 64 + i * 16 + l16) * 32 + quad * 8]);
            bf[i] = *reinterpret_cast<const bf16x8*>(&Bs[(wn * 64 + i * 16 + l16) * 32 + quad * 8]);
        }
        #pragma unroll
        for (int i = 0; i < 4; ++i)
            #pragma unroll
            for (int j = 0; j < 4; ++j)
                acc[i][j] = __builtin_amdgcn_mfma_f32_16x16x32_bf16(af[i], bf[j], acc[i][j], 0, 0, 0);
    }

    #pragma unroll
    for (int i = 0; i < 4; ++i) {
        const int mb = m0 + wm * 64 + i * 16 + quad * 4;
        #pragma unroll
        for (int j = 0; j < 4; ++j) {
            const int n = n0 + wn * 64 + j * 16 + l16;
            const float bv = bias[n];
            #pragma unroll
            for (int r = 0; r < 4; ++r) {
                const float val = acc[i][j][r] + bv;
                const int m = mb + r;
                if (mode == 0) {
                    outf[(size_t)m * C_ + n] = val;
                } else {
                    const int b = m >> 11, t = m & (T_ - 1);
                    const int h = n >> 6, d = n & 63;
                    outb[(((size_t)b * H_ + h) * T_ + t) * D_ + d] = f2b(val);
                }
            }
        }
    }
}

__global__ __launch_bounds__(256) void gemm_qkv(
    const unsigned short* __restrict__ A,
    const unsigned short* __restrict__ Wq, const unsigned short* __restrict__ Wk,
    const unsigned short* __restrict__ Wv,
    const float* __restrict__ bq, const float* __restrict__ bk,
    const float* __restrict__ bv,
    unsigned short* __restrict__ Qo, unsigned short* __restrict__ Ko,
    unsigned short* __restrict__ Vo)
{
    const int z = blockIdx.z;
    const unsigned short* Bt = z == 0 ? Wq : z == 1 ? Wk : Wv;
    const float* bias = z == 0 ? bq : z == 1 ? bk : bv;
    unsigned short* outb = z == 0 ? Qo : z == 1 ? Ko : Vo;
    gemm_core(A, Bt, bias, nullptr, outb, 1);
}

__global__ __launch_bounds__(256) void gemm_proj(
    const unsigned short* __restrict__ A, const unsigned short* __restrict__ Bt,
    const float* __restrict__ bias, float* __restrict__ outf)
{
    gemm_core(A, Bt, bias, outf, nullptr, 0);
}

// ---------------------------------------------------------------------------
// Rotary in-place on [B,H,T,D] bf16: one thread per (d, d+32) pair.
// ---------------------------------------------------------------------------
__global__ __launch_bounds__(256) void rotary2(unsigned short* Q)
{
    const int idx = blockIdx.x * 256 + threadIdx.x;   // over B*H*T*32 pairs
    const int j = idx & 31;
    const int row = idx >> 5;        // b*H*T + h*T + t
    const int t = row & (T_ - 1);
    const float inv = expf(-(float)j * (9.210340371976184f / 32.0f));  // 10000^{-j/32}
    const float ang = (float)t * inv;
    const float c = cosf(ang), s = sinf(ang);
    const int base = row * 64 + j;
    const float a = u2f(Q[base]);
    const float b = u2f(Q[base + 32]);
    Q[base]      = f2b(a * c - b * s);
    Q[base + 32] = f2b(b * c + a * s);
}

// ---------------------------------------------------------------------------
// Transpose V [BH, T, D] -> Vt [BH, D, T]  (bf16), 64x64 tiles.
// ---------------------------------------------------------------------------
__global__ __launch_bounds__(256) void transpose_v(
    const unsigned short* __restrict__ V, unsigned short* __restrict__ Vt)
{
    __shared__ __align__(16) unsigned short tile[64][72];
    const int t0 = blockIdx.x * 64;
    const int bh = blockIdx.y;
    const int tid = threadIdx.x;

    #pragma unroll
    for (int it = 0; it < 2; ++it) {
        const int idx = tid + it * 256;
        const int r = idx >> 3, ch = (idx & 7) * 8;
        *reinterpret_cast<bf16x8*>(&tile[r][ch]) =
            *reinterpret_cast<const bf16x8*>(V + ((size_t)bh * T_ + t0 + r) * D_ + ch);
    }
    __syncthreads();
    #pragma unroll
    for (int it = 0; it < 2; ++it) {
        const int idx = tid + it * 256;
        const int d = idx >> 3, ch = (idx & 7) * 8;
        unsigned short tmp[8];
        #pragma unroll
        for (int e = 0; e < 8; ++e) tmp[e] = tile[ch + e][d];
        *reinterpret_cast<bf16x8*>(Vt + ((size_t)bh * D_ + d) * T_ + t0 + ch) =
            *reinterpret_cast<const bf16x8*>(tmp);
    }
}

// ---------------------------------------------------------------------------
// Flash attention with MFMA bf16 16x16x32, precomputed distance-bias table.
// Block = 4 waves, one 64-row Q-tile of one (b,h). Writes Yb bf16 [B,T,C].
// ---------------------------------------------------------------------------
__global__ __launch_bounds__(256) void flash_attn(
    const unsigned short* __restrict__ Q, const unsigned short* __restrict__ K,
    const unsigned short* __restrict__ Vt, const float* __restrict__ dtab,
    unsigned short* __restrict__ Y)
{
    __shared__ __align__(16) unsigned short Ks[64][72];
    __shared__ __align__(16) unsigned short Vs[64][72];
    __shared__ __align__(16) unsigned short Ps[4][16][72];
    __shared__ float bias_row[T_];

    const int qt = blockIdx.x;
    const int bh = blockIdx.y;
    const int h = bh & (H_ - 1), b = bh >> 4;
    const int tid = threadIdx.x;
    const int wid = tid >> 6, lane = tid & 63;
    const int l16 = lane & 15, quad = lane >> 4;

    const size_t base = (size_t)bh * T_ * D_;
    const int q0 = qt * 64;
    const int arow = q0 + wid * 16 + l16;            // A-frag row (global)
    const int crow = q0 + wid * 16 + quad * 4;       // C-layout row base (+reg)

    // distance-bias row for this head (only distances 0..q0+63 occur)
    for (int ii = tid; ii < q0 + 64; ii += 256)
        bias_row[ii] = dtab[h * T_ + ii];

    bf16x8 qf[2];
    qf[0] = *reinterpret_cast<const bf16x8*>(Q + base + (size_t)arow * D_ + quad * 8);
    qf[1] = *reinterpret_cast<const bf16x8*>(Q + base + (size_t)arow * D_ + 32 + quad * 8);

    f32x4 o[4];
    #pragma unroll
    for (int c = 0; c < 4; ++c) o[c] = (f32x4){0.f, 0.f, 0.f, 0.f};
    float m_r[4] = {-INFINITY, -INFINITY, -INFINITY, -INFINITY};
    float l_r[4] = {0.f, 0.f, 0.f, 0.f};

    for (int kt = 0; kt <= qt; ++kt) {
        const int j0 = kt * 64;
        __syncthreads();   // previous iteration's LDS reads done (also covers bias_row fill)
        #pragma unroll
        for (int it = 0; it < 2; ++it) {
            const int idx = tid + it * 256;
            const int r = idx >> 3, ch = (idx & 7) * 8;
            *reinterpret_cast<bf16x8*>(&Ks[r][ch]) =
                *reinterpret_cast<const bf16x8*>(K + base + (size_t)(j0 + r) * D_ + ch);
            *reinterpret_cast<bf16x8*>(&Vs[r][ch]) =
                *reinterpret_cast<const bf16x8*>(Vt + ((size_t)bh * D_ + r) * T_ + j0 + ch);
        }
        __syncthreads();   // staging visible

        // ---- S = Q K^T (per wave: 16 rows x 64 cols) ----
        f32x4 sc[4];
        #pragma unroll
        for (int c = 0; c < 4; ++c) sc[c] = (f32x4){0.f, 0.f, 0.f, 0.f};
        #pragma unroll
        for (int c = 0; c < 4; ++c) {
            #pragma unroll
            for (int s = 0; s < 2; ++s) {
                bf16x8 kf = *reinterpret_cast<const bf16x8*>(&Ks[c * 16 + l16][s * 32 + quad * 8]);
                sc[c] = __builtin_amdgcn_mfma_f32_16x16x32_bf16(qf[s], kf, sc[c], 0, 0, 0);
            }
        }

        // ---- bias + causal mask, track row maxima ----
        float sv[4][4];
        float rmax[4] = {-INFINITY, -INFINITY, -INFINITY, -INFINITY};
        #pragma unroll
        for (int c = 0; c < 4; ++c) {
            const int jcol = j0 + c * 16 + l16;
            #pragma unroll
            for (int r = 0; r < 4; ++r) {
                const int n = (crow + r) - jcol;
                const float s = (n < 0) ? -INFINITY
                                        : (sc[c][r] + bias_row[n]) * 0.125f;
                sv[c][r] = s;
                rmax[r] = fmaxf(rmax[r], s);
            }
        }
        #pragma unroll
        for (int r = 0; r < 4; ++r) {
            #pragma unroll
            for (int off = 1; off < 16; off <<= 1)
                rmax[r] = fmaxf(rmax[r], __shfl_xor(rmax[r], off, 64));
        }

        // ---- online softmax update ----
        float alpha[4], rsum[4];
        #pragma unroll
        for (int r = 0; r < 4; ++r) {
            const float mn = fmaxf(m_r[r], rmax[r]);
            alpha[r] = expf(m_r[r] - mn);      // 0 on first tile (m=-inf)
            m_r[r] = mn;
            rsum[r] = 0.f;
        }
        #pragma unroll
        for (int c = 0; c < 4; ++c) {
            #pragma unroll
            for (int r = 0; r < 4; ++r) {
                const float p = expf(sv[c][r] - m_r[r]);   // masked -> 0
                rsum[r] += p;
                Ps[wid][quad * 4 + r][c * 16 + l16] = f2b(p);
            }
        }
        #pragma unroll
        for (int r = 0; r < 4; ++r) {
            #pragma unroll
            for (int off = 1; off < 16; off <<= 1)
                rsum[r] += __shfl_xor(rsum[r], off, 64);
            l_r[r] = l_r[r] * alpha[r] + rsum[r];
        }
        #pragma unroll
        for (int c = 0; c < 4; ++c) {
            #pragma unroll
            for (int r = 0; r < 4; ++r) o[c][r] *= alpha[r];
        }

        // ---- O += P V  (P from own-wave LDS region; wave-synchronous) ----
        #pragma unroll
        for (int s = 0; s < 2; ++s) {
            bf16x8 pf = *reinterpret_cast<const bf16x8*>(&Ps[wid][l16][s * 32 + quad * 8]);
            #pragma unroll
            for (int c = 0; c < 4; ++c) {
                bf16x8 vf = *reinterpret_cast<const bf16x8*>(&Vs[c * 16 + l16][s * 32 + quad * 8]);
                o[c] = __builtin_amdgcn_mfma_f32_16x16x32_bf16(pf, vf, o[c], 0, 0, 0);
            }
        }
    }

    // ---- epilogue: normalize and write Y [B,T,C] bf16 ----
    #pragma unroll
    for (int r = 0; r < 4; ++r) {
        const int i = crow + r;
        const float invl = 1.0f / l_r[r];
        #pragma unroll
        for (int c = 0; c < 4; ++c)
            Y[((size_t)b * T_ + i) * C_ + h * D_ + c * 16 + l16] = f2b(o[c][r] * invl);
    }
}

// ---------------------------------------------------------------------------
extern "C" void kernel_launch(void* const* d_in, const int* in_sizes, int n_in,
                              void* d_out, int out_size, void* d_ws, size_t ws_size,
                              hipStream_t stream)
{
    const float* x   = (const float*)d_in[0];
    const float* Wq  = (const float*)d_in[1];
    const float* bq  = (const float*)d_in[2];
    const float* Wk  = (const float*)d_in[3];
    const float* bk  = (const float*)d_in[4];
    const float* Wv  = (const float*)d_in[5];
    const float* bv  = (const float*)d_in[6];
    const float* Wp  = (const float*)d_in[7];
    const float* bp  = (const float*)d_in[8];
    const float* tbl = (const float*)d_in[9];
    float* out = (float*)d_out;

    const size_t n1 = (size_t)B_ * H_ * T_ * D_;       // 4,194,304
    const size_t nW = (size_t)C_ * C_;                 // 1,048,576
    unsigned short* xb  = (unsigned short*)d_ws;       // 8 MB
    unsigned short* Wqt = xb + (size_t)M_ * K_;        // 2 MB each
    unsigned short* Wkt = Wqt + nW;
    unsigned short* Wvt = Wkt + nW;
    unsigned short* Wpt = Wvt + nW;
    unsigned short* Qb  = Wpt + nW;                    // 8 MB each
    unsigned short* Kb  = Qb + n1;
    unsigned short* Vb  = Kb + n1;
    unsigned short* Vtb = Vb + n1;
    unsigned short* Yb  = Vtb + n1;
    float* dtab = (float*)(Yb + n1);                   // 128 KB   (~56.1 MB total)

    const dim3 blk(256);

    convert_x<<<(M_ * K_) / (256 * 8), blk, 0, stream>>>(x, xb);
    convert_w<<<dim3(16, 16, 4), blk, 0, stream>>>(Wq, Wk, Wv, Wp, Wqt, Wkt, Wvt, Wpt);
    build_bias<<<(H_ * T_) / 256, blk, 0, stream>>>(tbl, dtab);

    gemm_qkv<<<dim3(C_ / 128, M_ / 128, 3), blk, 0, stream>>>(
        xb, Wqt, Wkt, Wvt, bq, bk, bv, Qb, Kb, Vb);

    const int rot_blocks = (int)(n1 / 2 / 256);        // 8192
    rotary2<<<rot_blocks, blk, 0, stream>>>(Qb);
    rotary2<<<rot_blocks, blk, 0, stream>>>(Kb);

    transpose_v<<<dim3(T_ / 64, B_ * H_), blk, 0, stream>>>(Vb, Vtb);

    flash_attn<<<dim3(T_ / 64, B_ * H_), blk, 0, stream>>>(Qb, Kb, Vtb, dtab, Yb);

    gemm_proj<<<dim3(C_ / 128, M_ / 128), blk, 0, stream>>>(Yb, Wpt, bp, out);
}

// Round 5
// 257.365 us; speedup vs baseline: 19.7284x; 1.4201x over previous
//
#include <hip/hip_runtime.h>
#include <hip/hip_bf16.h>
#include <math.h>

#define B_ 2
#define T_ 2048
#define C_ 1024
#define H_ 16
#define D_ 64
#define M_ (B_ * T_)   // 4096
#define K_ 1024

// 0.125 * log2(e): folds the 1/sqrt(64) softmax scale into exp2-domain
#define SCALE2 0.18033688011112043f

typedef short bf16x8 __attribute__((ext_vector_type(8)));
typedef float f32x4  __attribute__((ext_vector_type(4)));
typedef unsigned int u32;

__device__ __forceinline__ float u2f(unsigned short u) {
    union { unsigned int i; float f; } v; v.i = ((unsigned int)u) << 16; return v.f;
}
__device__ __forceinline__ unsigned short f2b(float f) {
    __hip_bfloat16 h = __float2bfloat16(f);
    return *reinterpret_cast<unsigned short*>(&h);
}
// pack hi16(a),hi16(b) -> dword [b_hi:a_hi] with round-half-up (+0x8000)
__device__ __forceinline__ u32 pack_bf16_rnd(float a, float b) {
    const u32 au = __float_as_uint(a) + 0x8000u;
    const u32 bu = __float_as_uint(b) + 0x8000u;
    return __builtin_amdgcn_perm(bu, au, 0x07060302u);
}
__device__ __forceinline__ void load_lds16(const void* g, void* l) {
    __builtin_amdgcn_global_load_lds(
        (const __attribute__((address_space(1))) u32*)g,
        (__attribute__((address_space(3))) u32*)l, 16, 0, 0);
}

// ---------------------------------------------------------------------------
// convert x fp32 -> bf16 (8 elems/thread)
// ---------------------------------------------------------------------------
__global__ __launch_bounds__(256) void convert_x(
    const float* __restrict__ x, unsigned short* __restrict__ xb)
{
    const int idx = blockIdx.x * 256 + threadIdx.x;
    const float4 a = reinterpret_cast<const float4*>(x)[idx * 2];
    const float4 b = reinterpret_cast<const float4*>(x)[idx * 2 + 1];
    unsigned short t[8] = {f2b(a.x), f2b(a.y), f2b(a.z), f2b(a.w),
                           f2b(b.x), f2b(b.y), f2b(b.z), f2b(b.w)};
    reinterpret_cast<bf16x8*>(xb)[idx] = *reinterpret_cast<const bf16x8*>(t);
}

// ---------------------------------------------------------------------------
// convert + transpose W [K,N] fp32 -> Wt [N,K] bf16, 64x64 tiles, z picks W.
// ---------------------------------------------------------------------------
__global__ __launch_bounds__(256) void convert_w(
    const float* __restrict__ W0, const float* __restrict__ W1,
    const float* __restrict__ W2, const float* __restrict__ W3,
    unsigned short* __restrict__ T0, unsigned short* __restrict__ T1,
    unsigned short* __restrict__ T2, unsigned short* __restrict__ T3)
{
    __shared__ __align__(16) unsigned short tile[64][72];
    const int z = blockIdx.z;
    const float* W = z == 0 ? W0 : z == 1 ? W1 : z == 2 ? W2 : W3;
    unsigned short* Wt = z == 0 ? T0 : z == 1 ? T1 : z == 2 ? T2 : T3;
    const int k0 = blockIdx.x * 64, n0 = blockIdx.y * 64;
    const int tid = threadIdx.x;

    #pragma unroll
    for (int it = 0; it < 4; ++it) {
        const int idx = it * 256 + tid;
        const int r = idx >> 4, c = (idx & 15) * 4;
        const float4 w4 = *reinterpret_cast<const float4*>(W + (size_t)(k0 + r) * C_ + n0 + c);
        tile[r][c + 0] = f2b(w4.x); tile[r][c + 1] = f2b(w4.y);
        tile[r][c + 2] = f2b(w4.z); tile[r][c + 3] = f2b(w4.w);
    }
    __syncthreads();
    #pragma unroll
    for (int it = 0; it < 2; ++it) {
        const int idx = it * 256 + tid;
        const int nc = idx >> 3, kc = (idx & 7) * 8;
        unsigned short tmp[8];
        #pragma unroll
        for (int e = 0; e < 8; ++e) tmp[e] = tile[kc + e][nc];
        *reinterpret_cast<bf16x8*>(Wt + (size_t)(n0 + nc) * K_ + k0 + kc) =
            *reinterpret_cast<const bf16x8*>(tmp);
    }
}

// ---------------------------------------------------------------------------
// Precompute distance bias table in exp2 domain:
// dtab[h][n] = tbl[bucket(n)*H + h] * SCALE2
// ---------------------------------------------------------------------------
__global__ __launch_bounds__(256) void build_bias(
    const float* __restrict__ tbl, float* __restrict__ dtab)
{
    const int idx = blockIdx.x * 256 + threadIdx.x;   // 16*2048
    const int h = idx >> 11, n = idx & (T_ - 1);
    int bucket;
    if (n < 16) bucket = n;
    else {
        int vb = 16 + (int)(log2f((float)n * 0.0625f) * (16.0f / 3.0f));
        bucket = vb < 31 ? vb : 31;
    }
    dtab[idx] = tbl[bucket * H_ + h] * SCALE2;
}

// ---------------------------------------------------------------------------
// MFMA GEMM core: out[M,N] = A[M,K] @ Bt[N,K]^T + bias  (bf16 in, fp32 acc)
// 128x128 tile, BK=32, 4 waves (2x2), each wave 64x64 = 4x4 frags 16x16x32.
// mode 0: fp32 row-major [M,C] to outf
// mode 1: bf16 scatter to [B,H,T,D] outb  (Q,K)
// mode 2: bf16 V^T [B,H,D,T] packed b64 stores to outb  (V)
// ---------------------------------------------------------------------------
__device__ __forceinline__ void gemm_core(
    const unsigned short* __restrict__ A, const unsigned short* __restrict__ Bt,
    const float* __restrict__ bias, float* __restrict__ outf,
    unsigned short* __restrict__ outb, int mode)
{
    __shared__ __align__(16) unsigned short As[128 * 32];
    __shared__ __align__(16) unsigned short Bs[128 * 32];

    const int tid = threadIdx.x;
    const int wid = tid >> 6, lane = tid & 63;
    const int l16 = lane & 15, quad = lane >> 4;
    const int wm = wid >> 1, wn = wid & 1;
    const int m0 = blockIdx.y * 128, n0 = blockIdx.x * 128;

    f32x4 acc[4][4];
    #pragma unroll
    for (int i = 0; i < 4; ++i)
        #pragma unroll
        for (int j = 0; j < 4; ++j) acc[i][j] = (f32x4){0.f, 0.f, 0.f, 0.f};

    char* AsB = (char*)As;
    char* BsB = (char*)Bs;

    for (int k0 = 0; k0 < K_; k0 += 32) {
        __syncthreads();
        #pragma unroll
        for (int it = 0; it < 2; ++it) {
            const int idx = it * 256 + tid;
            const int row = idx >> 2, ch = (idx & 3) * 8;
            const int ldso = it * 4096 + wid * 1024;       // wave-uniform
            load_lds16(A + (size_t)(m0 + row) * K_ + k0 + ch, AsB + ldso);
            load_lds16(Bt + (size_t)(n0 + row) * K_ + k0 + ch, BsB + ldso);
        }
        __syncthreads();

        bf16x8 af[4], bf[4];
        #pragma unroll
        for (int i = 0; i < 4; ++i) {
            af[i] = *reinterpret_cast<const bf16x8*>(&As[(wm * 64 + i * 16 + l16) * 32 + quad * 8]);
            bf[i] = *reinterpret_cast<const bf16x8*>(&Bs[(wn * 64 + i * 16 + l16) * 32 + quad * 8]);
        }
        #pragma unroll
        for (int i = 0; i < 4; ++i)
            #pragma unroll
            for (int j = 0; j < 4; ++j)
                acc[i][j] = __builtin_amdgcn_mfma_f32_16x16x32_bf16(af[i], bf[j], acc[i][j], 0, 0, 0);
    }

    #pragma unroll
    for (int i = 0; i < 4; ++i) {
        const int mb = m0 + wm * 64 + i * 16 + quad * 4;
        #pragma unroll
        for (int j = 0; j < 4; ++j) {
            const int n = n0 + wn * 64 + j * 16 + l16;
            const float bv = bias[n];
            if (mode == 2) {
                // V^T: 4 consecutive t at fixed (h,d) -> one 8B store
                const int bb = mb >> 11, t = mb & (T_ - 1);
                const int h = n >> 6, d = n & 63;
                uint2 w;
                w.x = pack_bf16_rnd(acc[i][j][0] + bv, acc[i][j][1] + bv);
                w.y = pack_bf16_rnd(acc[i][j][2] + bv, acc[i][j][3] + bv);
                *reinterpret_cast<uint2*>(
                    outb + (((size_t)bb * H_ + h) * D_ + d) * T_ + t) = w;
            } else {
                #pragma unroll
                for (int r = 0; r < 4; ++r) {
                    const float val = acc[i][j][r] + bv;
                    const int m = mb + r;
                    if (mode == 0) {
                        outf[(size_t)m * C_ + n] = val;
                    } else {
                        const int b = m >> 11, t = m & (T_ - 1);
                        const int h = n >> 6, d = n & 63;
                        outb[(((size_t)b * H_ + h) * T_ + t) * D_ + d] = f2b(val);
                    }
                }
            }
        }
    }
}

__global__ __launch_bounds__(256) void gemm_qkv(
    const unsigned short* __restrict__ A,
    const unsigned short* __restrict__ Wq, const unsigned short* __restrict__ Wk,
    const unsigned short* __restrict__ Wv,
    const float* __restrict__ bq, const float* __restrict__ bk,
    const float* __restrict__ bv,
    unsigned short* __restrict__ Qo, unsigned short* __restrict__ Ko,
    unsigned short* __restrict__ Vto)
{
    const int z = blockIdx.z;
    const unsigned short* Bt = z == 0 ? Wq : z == 1 ? Wk : Wv;
    const float* bias = z == 0 ? bq : z == 1 ? bk : bv;
    unsigned short* outb = z == 0 ? Qo : z == 1 ? Ko : Vto;
    gemm_core(A, Bt, bias, nullptr, outb, z == 2 ? 2 : 1);
}

__global__ __launch_bounds__(256) void gemm_proj(
    const unsigned short* __restrict__ A, const unsigned short* __restrict__ Bt,
    const float* __restrict__ bias, float* __restrict__ outf)
{
    gemm_core(A, Bt, bias, outf, nullptr, 0);
}

// ---------------------------------------------------------------------------
// Rotary in-place on [B,H,T,D] bf16: one thread per (d, d+32) pair.
// `scale` folds the softmax/exp2 constant into Q (1.0 for K).
// ---------------------------------------------------------------------------
__global__ __launch_bounds__(256) void rotary2(unsigned short* Q, float scale)
{
    const int idx = blockIdx.x * 256 + threadIdx.x;   // over B*H*T*32 pairs
    const int j = idx & 31;
    const int row = idx >> 5;        // b*H*T + h*T + t
    const int t = row & (T_ - 1);
    const float inv = expf(-(float)j * (9.210340371976184f / 32.0f));  // 10000^{-j/32}
    const float ang = (float)t * inv;
    const float c = cosf(ang) * scale, s = sinf(ang) * scale;
    const int base = row * 64 + j;
    const float a = u2f(Q[base]);
    const float b = u2f(Q[base + 32]);
    Q[base]      = f2b(a * c - b * s);
    Q[base + 32] = f2b(b * c + a * s);
}

// ---------------------------------------------------------------------------
// Flash attention, MFMA bf16 16x16x32, exp2-domain softmax.
// Grid (16, BH): block p handles Q-tiles p and 31-p  -> uniform 33 k-tiles.
// Keys permuted within 64-tiles (key = l16*4 + c) so P packs to b64 writes.
// Row-sum accumulated via ones-column MFMA; bias via shifted LDS table
// (indices [0,64) = -inf) -> no mask branches.
// ---------------------------------------------------------------------------
__global__ __launch_bounds__(256) void flash_attn(
    const unsigned short* __restrict__ Q, const unsigned short* __restrict__ K,
    const unsigned short* __restrict__ Vt, const float* __restrict__ dtab,
    unsigned short* __restrict__ Y)
{
    __shared__ __align__(16) unsigned short Ks[64][72];
    __shared__ __align__(16) unsigned short Vs[64][72];
    __shared__ __align__(16) unsigned short Ps[4][16][72];
    __shared__ float bias_ls[64 + T_];

    const int p = blockIdx.x;               // 0..15
    const int bh = blockIdx.y;
    const int h = bh & (H_ - 1), b = bh >> 4;
    const int tid = threadIdx.x;
    const int wid = tid >> 6, lane = tid & 63;
    const int l16 = lane & 15, quad = lane >> 4;
    const size_t base = (size_t)bh * T_ * D_;

    // shifted bias table: bias_ls[64+n] = dtab[h][n]; [0,64) = -inf
    if (tid < 64) bias_ls[tid] = -INFINITY;
    for (int ii = tid; ii < T_; ii += 256) bias_ls[64 + ii] = dtab[h * T_ + ii];

    bf16x8 ones;
    #pragma unroll
    for (int e = 0; e < 8; ++e) ones[e] = (short)0x3F80;   // bf16 1.0

    #pragma unroll 1
    for (int pass = 0; pass < 2; ++pass) {
        const int qt = pass ? (31 - p) : p;
        const int q0 = qt * 64;
        const int arow = q0 + wid * 16 + l16;            // A-frag row (global)
        const int crow = q0 + wid * 16 + quad * 4;       // C-layout row base
        const int nbase = crow - l16 * 4;                // n = nbase - j0 - c + r

        bf16x8 qf[2];
        qf[0] = *reinterpret_cast<const bf16x8*>(Q + base + (size_t)arow * D_ + quad * 8);
        qf[1] = *reinterpret_cast<const bf16x8*>(Q + base + (size_t)arow * D_ + 32 + quad * 8);

        f32x4 o[4], ol;
        #pragma unroll
        for (int c = 0; c < 4; ++c) o[c] = (f32x4){0.f, 0.f, 0.f, 0.f};
        ol = (f32x4){0.f, 0.f, 0.f, 0.f};
        float m2[4] = {-INFINITY, -INFINITY, -INFINITY, -INFINITY};

        for (int kt = 0; kt <= qt; ++kt) {
            const int j0 = kt * 64;
            __syncthreads();   // prior LDS reads (and bias fill) complete
            #pragma unroll
            for (int it = 0; it < 2; ++it) {
                const int idx = tid + it * 256;
                const int r = idx >> 3, ch = (idx & 7) * 8;
                *reinterpret_cast<bf16x8*>(&Ks[r][ch]) =
                    *reinterpret_cast<const bf16x8*>(K + base + (size_t)(j0 + r) * D_ + ch);
                *reinterpret_cast<bf16x8*>(&Vs[r][ch]) =
                    *reinterpret_cast<const bf16x8*>(Vt + ((size_t)bh * D_ + r) * T_ + j0 + ch);
            }
            __syncthreads();   // staging visible

            // ---- S = Q K^T, key-permuted: tile c covers keys l16*4+c ----
            f32x4 sc[4];
            #pragma unroll
            for (int c = 0; c < 4; ++c) sc[c] = (f32x4){0.f, 0.f, 0.f, 0.f};
            #pragma unroll
            for (int c = 0; c < 4; ++c) {
                #pragma unroll
                for (int s = 0; s < 2; ++s) {
                    bf16x8 kf = *reinterpret_cast<const bf16x8*>(
                        &Ks[l16 * 4 + c][s * 32 + quad * 8]);
                    sc[c] = __builtin_amdgcn_mfma_f32_16x16x32_bf16(qf[s], kf, sc[c], 0, 0, 0);
                }
            }

            // ---- bias (shifted table handles causal mask), row maxima ----
            float sv[4][4];
            float rmax[4] = {-INFINITY, -INFINITY, -INFINITY, -INFINITY};
            #pragma unroll
            for (int c = 0; c < 4; ++c) {
                const float* bptr = &bias_ls[64 + nbase - j0 - c];
                #pragma unroll
                for (int r = 0; r < 4; ++r) {
                    const float s2 = sc[c][r] + bptr[r];
                    sv[c][r] = s2;
                    rmax[r] = fmaxf(rmax[r], s2);
                }
            }
            #pragma unroll
            for (int r = 0; r < 4; ++r) {
                #pragma unroll
                for (int off = 1; off < 16; off <<= 1)
                    rmax[r] = fmaxf(rmax[r], __shfl_xor(rmax[r], off, 64));
            }

            // ---- online softmax (exp2 domain) ----
            float alpha[4];
            #pragma unroll
            for (int r = 0; r < 4; ++r) {
                const float mn = fmaxf(m2[r], rmax[r]);
                alpha[r] = exp2f(m2[r] - mn);      // 0 on first tile
                m2[r] = mn;
            }
            #pragma unroll
            for (int r = 0; r < 4; ++r) {
                float p0 = exp2f(sv[0][r] - m2[r]);
                float p1 = exp2f(sv[1][r] - m2[r]);
                float p2 = exp2f(sv[2][r] - m2[r]);
                float p3 = exp2f(sv[3][r] - m2[r]);
                uint2 w;
                w.x = pack_bf16_rnd(p0, p1);
                w.y = pack_bf16_rnd(p2, p3);
                *reinterpret_cast<uint2*>(&Ps[wid][quad * 4 + r][l16 * 4]) = w;
            }
            #pragma unroll
            for (int c = 0; c < 4; ++c) {
                #pragma unroll
                for (int r = 0; r < 4; ++r) o[c][r] *= alpha[r];
            }
            #pragma unroll
            for (int r = 0; r < 4; ++r) ol[r] *= alpha[r];

            // ---- O += P V; row-sum via ones-column MFMA ----
            #pragma unroll
            for (int s = 0; s < 2; ++s) {
                bf16x8 pf = *reinterpret_cast<const bf16x8*>(&Ps[wid][l16][s * 32 + quad * 8]);
                #pragma unroll
                for (int c = 0; c < 4; ++c) {
                    bf16x8 vf = *reinterpret_cast<const bf16x8*>(&Vs[c * 16 + l16][s * 32 + quad * 8]);
                    o[c] = __builtin_amdgcn_mfma_f32_16x16x32_bf16(pf, vf, o[c], 0, 0, 0);
                }
                ol = __builtin_amdgcn_mfma_f32_16x16x32_bf16(pf, ones, ol, 0, 0, 0);
            }
        }

        // ---- epilogue: normalize and write Y [B,T,C] bf16 ----
        #pragma unroll
        for (int r = 0; r < 4; ++r) {
            const int i = crow + r;
            const float invl = 1.0f / ol[r];
            #pragma unroll
            for (int c = 0; c < 4; ++c)
                Y[((size_t)b * T_ + i) * C_ + h * D_ + c * 16 + l16] = f2b(o[c][r] * invl);
        }
    }
}

// ---------------------------------------------------------------------------
extern "C" void kernel_launch(void* const* d_in, const int* in_sizes, int n_in,
                              void* d_out, int out_size, void* d_ws, size_t ws_size,
                              hipStream_t stream)
{
    const float* x   = (const float*)d_in[0];
    const float* Wq  = (const float*)d_in[1];
    const float* bq  = (const float*)d_in[2];
    const float* Wk  = (const float*)d_in[3];
    const float* bk  = (const float*)d_in[4];
    const float* Wv  = (const float*)d_in[5];
    const float* bv  = (const float*)d_in[6];
    const float* Wp  = (const float*)d_in[7];
    const float* bp  = (const float*)d_in[8];
    const float* tbl = (const float*)d_in[9];
    float* out = (float*)d_out;

    const size_t n1 = (size_t)B_ * H_ * T_ * D_;       // 4,194,304
    const size_t nW = (size_t)C_ * C_;                 // 1,048,576
    unsigned short* xb  = (unsigned short*)d_ws;       // 8 MB
    unsigned short* Wqt = xb + (size_t)M_ * K_;        // 2 MB each
    unsigned short* Wkt = Wqt + nW;
    unsigned short* Wvt = Wkt + nW;
    unsigned short* Wpt = Wvt + nW;
    unsigned short* Qb  = Wpt + nW;                    // 8 MB each
    unsigned short* Kb  = Qb + n1;
    unsigned short* Vtb = Kb + n1;                     // V^T, written by gemm_qkv
    unsigned short* Yb  = Vtb + n1;
    float* dtab = (float*)(Yb + n1);                   // 128 KB (~48 MB total)

    const dim3 blk(256);

    convert_x<<<(M_ * K_) / (256 * 8), blk, 0, stream>>>(x, xb);
    convert_w<<<dim3(16, 16, 4), blk, 0, stream>>>(Wq, Wk, Wv, Wp, Wqt, Wkt, Wvt, Wpt);
    build_bias<<<(H_ * T_) / 256, blk, 0, stream>>>(tbl, dtab);

    gemm_qkv<<<dim3(C_ / 128, M_ / 128, 3), blk, 0, stream>>>(
        xb, Wqt, Wkt, Wvt, bq, bk, bv, Qb, Kb, Vtb);

    const int rot_blocks = (int)(n1 / 2 / 256);        // 8192
    rotary2<<<rot_blocks, blk, 0, stream>>>(Qb, SCALE2);
    rotary2<<<rot_blocks, blk, 0, stream>>>(Kb, 1.0f);

    flash_attn<<<dim3(16, B_ * H_), blk, 0, stream>>>(Qb, Kb, Vtb, dtab, Yb);

    gemm_proj<<<dim3(C_ / 128, M_ / 128), blk, 0, stream>>>(Yb, Wpt, bp, out);
}

// Round 6
// 256.878 us; speedup vs baseline: 19.7658x; 1.0019x over previous
//
#include <hip/hip_runtime.h>
#include <hip/hip_bf16.h>
#include <math.h>

#define B_ 2
#define T_ 2048
#define C_ 1024
#define H_ 16
#define D_ 64
#define M_ (B_ * T_)   // 4096
#define K_ 1024

// 0.125 * log2(e): folds the 1/sqrt(64) softmax scale into exp2-domain
#define SCALE2 0.18033688011112043f

typedef short bf16x8 __attribute__((ext_vector_type(8)));
typedef float f32x4  __attribute__((ext_vector_type(4)));
typedef unsigned int u32;

__device__ __forceinline__ float u2f(unsigned short u) {
    union { unsigned int i; float f; } v; v.i = ((unsigned int)u) << 16; return v.f;
}
__device__ __forceinline__ unsigned short f2b(float f) {
    __hip_bfloat16 h = __float2bfloat16(f);
    return *reinterpret_cast<unsigned short*>(&h);
}
// pack hi16(a),hi16(b) -> dword [b_hi:a_hi] with round-half-up (+0x8000)
__device__ __forceinline__ u32 pack_bf16_rnd(float a, float b) {
    const u32 au = __float_as_uint(a) + 0x8000u;
    const u32 bu = __float_as_uint(b) + 0x8000u;
    return __builtin_amdgcn_perm(bu, au, 0x07060302u);
}
__device__ __forceinline__ void load_lds16(const void* g, void* l) {
    __builtin_amdgcn_global_load_lds(
        (const __attribute__((address_space(1))) u32*)g,
        (__attribute__((address_space(3))) u32*)l, 16, 0, 0);
}

// ---------------------------------------------------------------------------
// convert x fp32 -> bf16 (8 elems/thread)
// ---------------------------------------------------------------------------
__global__ __launch_bounds__(256) void convert_x(
    const float* __restrict__ x, unsigned short* __restrict__ xb)
{
    const int idx = blockIdx.x * 256 + threadIdx.x;
    const float4 a = reinterpret_cast<const float4*>(x)[idx * 2];
    const float4 b = reinterpret_cast<const float4*>(x)[idx * 2 + 1];
    unsigned short t[8] = {f2b(a.x), f2b(a.y), f2b(a.z), f2b(a.w),
                           f2b(b.x), f2b(b.y), f2b(b.z), f2b(b.w)};
    reinterpret_cast<bf16x8*>(xb)[idx] = *reinterpret_cast<const bf16x8*>(t);
}

// ---------------------------------------------------------------------------
// convert + transpose W [K,N] fp32 -> Wt [N,K] bf16, 64x64 tiles, z picks W.
// ---------------------------------------------------------------------------
__global__ __launch_bounds__(256) void convert_w(
    const float* __restrict__ W0, const float* __restrict__ W1,
    const float* __restrict__ W2, const float* __restrict__ W3,
    unsigned short* __restrict__ T0, unsigned short* __restrict__ T1,
    unsigned short* __restrict__ T2, unsigned short* __restrict__ T3)
{
    __shared__ __align__(16) unsigned short tile[64][72];
    const int z = blockIdx.z;
    const float* W = z == 0 ? W0 : z == 1 ? W1 : z == 2 ? W2 : W3;
    unsigned short* Wt = z == 0 ? T0 : z == 1 ? T1 : z == 2 ? T2 : T3;
    const int k0 = blockIdx.x * 64, n0 = blockIdx.y * 64;
    const int tid = threadIdx.x;

    #pragma unroll
    for (int it = 0; it < 4; ++it) {
        const int idx = it * 256 + tid;
        const int r = idx >> 4, c = (idx & 15) * 4;
        const float4 w4 = *reinterpret_cast<const float4*>(W + (size_t)(k0 + r) * C_ + n0 + c);
        tile[r][c + 0] = f2b(w4.x); tile[r][c + 1] = f2b(w4.y);
        tile[r][c + 2] = f2b(w4.z); tile[r][c + 3] = f2b(w4.w);
    }
    __syncthreads();
    #pragma unroll
    for (int it = 0; it < 2; ++it) {
        const int idx = it * 256 + tid;
        const int nc = idx >> 3, kc = (idx & 7) * 8;
        unsigned short tmp[8];
        #pragma unroll
        for (int e = 0; e < 8; ++e) tmp[e] = tile[kc + e][nc];
        *reinterpret_cast<bf16x8*>(Wt + (size_t)(n0 + nc) * K_ + k0 + kc) =
            *reinterpret_cast<const bf16x8*>(tmp);
    }
}

// ---------------------------------------------------------------------------
// Precompute (a) distance bias table (exp2 domain) and (b) rotary trig table.
// dtab[h][n] = tbl[bucket(n)*H + h] * SCALE2       (idx < 32768)
// trig[t*32+j] = (cos(t*invf[j]), sin(t*invf[j]))  (idx < 65536)
// ---------------------------------------------------------------------------
__global__ __launch_bounds__(256) void build_tabs(
    const float* __restrict__ tbl, float* __restrict__ dtab,
    float2* __restrict__ trig)
{
    const int idx = blockIdx.x * 256 + threadIdx.x;   // 0..65535
    if (idx < H_ * T_) {
        const int h = idx >> 11, n = idx & (T_ - 1);
        int bucket;
        if (n < 16) bucket = n;
        else {
            int vb = 16 + (int)(log2f((float)n * 0.0625f) * (16.0f / 3.0f));
            bucket = vb < 31 ? vb : 31;
        }
        dtab[idx] = tbl[bucket * H_ + h] * SCALE2;
    }
    const int t = idx >> 5, j = idx & 31;
    // inv_freq = 10000^{-j/32} = 2^{-j*log2(10000)/32}
    const float inv = exp2f(-(float)j * (13.287712379549449f / 32.0f));
    const float ang = (float)t * inv;
    trig[idx] = make_float2(cosf(ang), sinf(ang));
}

// ---------------------------------------------------------------------------
// MFMA GEMM core: out[M,N] = A[M,K] @ Bt[N,K]^T + bias  (bf16 in, fp32 acc)
// 128x128 tile, BK=32, 4 waves (2x2), each wave 64x64 = 4x4 frags 16x16x32.
// mode 0: fp32 row-major [M,C] to outf
// mode 1: rotary applied in registers, bf16 scatter to [B,H,T,D] (Q,K);
//         rot_scale folds SCALE2 into Q.
// mode 2: bf16 V^T [B,H,D,T] packed b64 stores (V)
// ---------------------------------------------------------------------------
__device__ __forceinline__ void gemm_core(
    const unsigned short* __restrict__ A, const unsigned short* __restrict__ Bt,
    const float* __restrict__ bias, const float2* __restrict__ trig,
    float rot_scale, float* __restrict__ outf,
    unsigned short* __restrict__ outb, int mode)
{
    __shared__ __align__(16) unsigned short As[128 * 32];
    __shared__ __align__(16) unsigned short Bs[128 * 32];

    const int tid = threadIdx.x;
    const int wid = tid >> 6, lane = tid & 63;
    const int l16 = lane & 15, quad = lane >> 4;
    const int wm = wid >> 1, wn = wid & 1;
    const int m0 = blockIdx.y * 128, n0 = blockIdx.x * 128;

    f32x4 acc[4][4];
    #pragma unroll
    for (int i = 0; i < 4; ++i)
        #pragma unroll
        for (int j = 0; j < 4; ++j) acc[i][j] = (f32x4){0.f, 0.f, 0.f, 0.f};

    char* AsB = (char*)As;
    char* BsB = (char*)Bs;

    for (int k0 = 0; k0 < K_; k0 += 32) {
        __syncthreads();
        #pragma unroll
        for (int it = 0; it < 2; ++it) {
            const int idx = it * 256 + tid;
            const int row = idx >> 2, ch = (idx & 3) * 8;
            const int ldso = it * 4096 + wid * 1024;       // wave-uniform
            load_lds16(A + (size_t)(m0 + row) * K_ + k0 + ch, AsB + ldso);
            load_lds16(Bt + (size_t)(n0 + row) * K_ + k0 + ch, BsB + ldso);
        }
        __syncthreads();

        bf16x8 af[4], bf[4];
        #pragma unroll
        for (int i = 0; i < 4; ++i) {
            af[i] = *reinterpret_cast<const bf16x8*>(&As[(wm * 64 + i * 16 + l16) * 32 + quad * 8]);
            bf[i] = *reinterpret_cast<const bf16x8*>(&Bs[(wn * 64 + i * 16 + l16) * 32 + quad * 8]);
        }
        #pragma unroll
        for (int i = 0; i < 4; ++i)
            #pragma unroll
            for (int j = 0; j < 4; ++j)
                acc[i][j] = __builtin_amdgcn_mfma_f32_16x16x32_bf16(af[i], bf[j], acc[i][j], 0, 0, 0);
    }

    if (mode == 1) {
        // rotary in registers: pair (acc[i][jc], acc[i][jc+2]) = dims (d, d+32)
        #pragma unroll
        for (int i = 0; i < 4; ++i) {
            const int mb = m0 + wm * 64 + i * 16 + quad * 4;
            const int bb = mb >> 11, tb = mb & (T_ - 1);
            #pragma unroll
            for (int jc = 0; jc < 2; ++jc) {
                const int n_lo = n0 + wn * 64 + jc * 16 + l16;
                const int h = n_lo >> 6, d = n_lo & 63;     // d < 32
                const float bv_lo = bias[n_lo], bv_hi = bias[n_lo + 32];
                unsigned short* po = outb + (((size_t)bb * H_ + h) * T_ + tb) * D_ + d;
                #pragma unroll
                for (int r = 0; r < 4; ++r) {
                    const float2 cs = trig[(tb + r) * 32 + d];
                    const float a = acc[i][jc][r] + bv_lo;
                    const float b = acc[i][jc + 2][r] + bv_hi;
                    po[(size_t)r * D_]      = f2b((a * cs.x - b * cs.y) * rot_scale);
                    po[(size_t)r * D_ + 32] = f2b((b * cs.x + a * cs.y) * rot_scale);
                }
            }
        }
        return;
    }

    #pragma unroll
    for (int i = 0; i < 4; ++i) {
        const int mb = m0 + wm * 64 + i * 16 + quad * 4;
        #pragma unroll
        for (int j = 0; j < 4; ++j) {
            const int n = n0 + wn * 64 + j * 16 + l16;
            const float bv = bias[n];
            if (mode == 2) {
                // V^T: 4 consecutive t at fixed (h,d) -> one 8B store
                const int bb = mb >> 11, t = mb & (T_ - 1);
                const int h = n >> 6, d = n & 63;
                uint2 w;
                w.x = pack_bf16_rnd(acc[i][j][0] + bv, acc[i][j][1] + bv);
                w.y = pack_bf16_rnd(acc[i][j][2] + bv, acc[i][j][3] + bv);
                *reinterpret_cast<uint2*>(
                    outb + (((size_t)bb * H_ + h) * D_ + d) * T_ + t) = w;
            } else {
                #pragma unroll
                for (int r = 0; r < 4; ++r)
                    outf[(size_t)(mb + r) * C_ + n] = acc[i][j][r] + bv;
            }
        }
    }
}

__global__ __launch_bounds__(256) void gemm_qkv(
    const unsigned short* __restrict__ A,
    const unsigned short* __restrict__ Wq, const unsigned short* __restrict__ Wk,
    const unsigned short* __restrict__ Wv,
    const float* __restrict__ bq, const float* __restrict__ bk,
    const float* __restrict__ bv, const float2* __restrict__ trig,
    unsigned short* __restrict__ Qo, unsigned short* __restrict__ Ko,
    unsigned short* __restrict__ Vto)
{
    const int z = blockIdx.z;
    const unsigned short* Bt = z == 0 ? Wq : z == 1 ? Wk : Wv;
    const float* bias = z == 0 ? bq : z == 1 ? bk : bv;
    unsigned short* outb = z == 0 ? Qo : z == 1 ? Ko : Vto;
    const float rs = z == 0 ? SCALE2 : 1.0f;
    gemm_core(A, Bt, bias, trig, rs, nullptr, outb, z == 2 ? 2 : 1);
}

__global__ __launch_bounds__(256) void gemm_proj(
    const unsigned short* __restrict__ A, const unsigned short* __restrict__ Bt,
    const float* __restrict__ bias, float* __restrict__ outf)
{
    gemm_core(A, Bt, bias, nullptr, 1.0f, outf, nullptr, 0);
}

// ---------------------------------------------------------------------------
// Flash attention, MFMA bf16 16x16x32, exp2-domain softmax.
// Grid (32, BH): qt = (bx + bh) & 31 -> each CU's 4 resident blocks get
// mixed tile sizes (load spread 52..80 vs 4..128 unswizzled).
// Keys permuted within 64-tiles (key = l16*4 + c) so P packs to b64 writes.
// Row-sum via ones-column MFMA; causal mask via shifted bias table in LDS.
// ---------------------------------------------------------------------------
__global__ __launch_bounds__(256) void flash_attn(
    const unsigned short* __restrict__ Q, const unsigned short* __restrict__ K,
    const unsigned short* __restrict__ Vt, const float* __restrict__ dtab,
    unsigned short* __restrict__ Y)
{
    __shared__ __align__(16) unsigned short Ks[64][72];
    __shared__ __align__(16) unsigned short Vs[64][72];
    __shared__ __align__(16) unsigned short Ps[4][16][72];
    __shared__ float bias_ls[64 + T_];

    const int bh = blockIdx.y;
    const int qt = (int)((blockIdx.x + blockIdx.y) & 31);
    const int h = bh & (H_ - 1), b = bh >> 4;
    const int tid = threadIdx.x;
    const int wid = tid >> 6, lane = tid & 63;
    const int l16 = lane & 15, quad = lane >> 4;
    const size_t base = (size_t)bh * T_ * D_;

    // shifted bias table: bias_ls[64+n] = dtab[h][n]; [0,64) = -inf
    if (tid < 64) bias_ls[tid] = -INFINITY;
    for (int ii = tid; ii < T_; ii += 256) bias_ls[64 + ii] = dtab[h * T_ + ii];

    bf16x8 ones;
    #pragma unroll
    for (int e = 0; e < 8; ++e) ones[e] = (short)0x3F80;   // bf16 1.0

    const int q0 = qt * 64;
    const int arow = q0 + wid * 16 + l16;            // A-frag row (global)
    const int crow = q0 + wid * 16 + quad * 4;       // C-layout row base
    const int nbase = crow - l16 * 4;                // n = nbase - j0 - c + r

    bf16x8 qf[2];
    qf[0] = *reinterpret_cast<const bf16x8*>(Q + base + (size_t)arow * D_ + quad * 8);
    qf[1] = *reinterpret_cast<const bf16x8*>(Q + base + (size_t)arow * D_ + 32 + quad * 8);

    f32x4 o[4], ol;
    #pragma unroll
    for (int c = 0; c < 4; ++c) o[c] = (f32x4){0.f, 0.f, 0.f, 0.f};
    ol = (f32x4){0.f, 0.f, 0.f, 0.f};
    float m2[4] = {-INFINITY, -INFINITY, -INFINITY, -INFINITY};

    for (int kt = 0; kt <= qt; ++kt) {
        const int j0 = kt * 64;
        __syncthreads();   // prior LDS reads (and bias fill) complete
        #pragma unroll
        for (int it = 0; it < 2; ++it) {
            const int idx = tid + it * 256;
            const int r = idx >> 3, ch = (idx & 7) * 8;
            *reinterpret_cast<bf16x8*>(&Ks[r][ch]) =
                *reinterpret_cast<const bf16x8*>(K + base + (size_t)(j0 + r) * D_ + ch);
            *reinterpret_cast<bf16x8*>(&Vs[r][ch]) =
                *reinterpret_cast<const bf16x8*>(Vt + ((size_t)bh * D_ + r) * T_ + j0 + ch);
        }
        __syncthreads();   // staging visible

        // ---- S = Q K^T, key-permuted: tile c covers keys l16*4+c ----
        f32x4 sc[4];
        #pragma unroll
        for (int c = 0; c < 4; ++c) sc[c] = (f32x4){0.f, 0.f, 0.f, 0.f};
        #pragma unroll
        for (int c = 0; c < 4; ++c) {
            #pragma unroll
            for (int s = 0; s < 2; ++s) {
                bf16x8 kf = *reinterpret_cast<const bf16x8*>(
                    &Ks[l16 * 4 + c][s * 32 + quad * 8]);
                sc[c] = __builtin_amdgcn_mfma_f32_16x16x32_bf16(qf[s], kf, sc[c], 0, 0, 0);
            }
        }

        // ---- bias (shifted table handles causal mask), row maxima ----
        float sv[4][4];
        float rmax[4] = {-INFINITY, -INFINITY, -INFINITY, -INFINITY};
        #pragma unroll
        for (int c = 0; c < 4; ++c) {
            const float* bptr = &bias_ls[64 + nbase - j0 - c];
            #pragma unroll
            for (int r = 0; r < 4; ++r) {
                const float s2 = sc[c][r] + bptr[r];
                sv[c][r] = s2;
                rmax[r] = fmaxf(rmax[r], s2);
            }
        }
        #pragma unroll
        for (int r = 0; r < 4; ++r) {
            #pragma unroll
            for (int off = 1; off < 16; off <<= 1)
                rmax[r] = fmaxf(rmax[r], __shfl_xor(rmax[r], off, 64));
        }

        // ---- online softmax (exp2 domain) ----
        float alpha[4];
        #pragma unroll
        for (int r = 0; r < 4; ++r) {
            const float mn = fmaxf(m2[r], rmax[r]);
            alpha[r] = exp2f(m2[r] - mn);      // 0 on first tile
            m2[r] = mn;
        }
        #pragma unroll
        for (int r = 0; r < 4; ++r) {
            float p0 = exp2f(sv[0][r] - m2[r]);
            float p1 = exp2f(sv[1][r] - m2[r]);
            float p2 = exp2f(sv[2][r] - m2[r]);
            float p3 = exp2f(sv[3][r] - m2[r]);
            uint2 w;
            w.x = pack_bf16_rnd(p0, p1);
            w.y = pack_bf16_rnd(p2, p3);
            *reinterpret_cast<uint2*>(&Ps[wid][quad * 4 + r][l16 * 4]) = w;
        }
        #pragma unroll
        for (int c = 0; c < 4; ++c) {
            #pragma unroll
            for (int r = 0; r < 4; ++r) o[c][r] *= alpha[r];
        }
        #pragma unroll
        for (int r = 0; r < 4; ++r) ol[r] *= alpha[r];

        // ---- O += P V; row-sum via ones-column MFMA ----
        #pragma unroll
        for (int s = 0; s < 2; ++s) {
            bf16x8 pf = *reinterpret_cast<const bf16x8*>(&Ps[wid][l16][s * 32 + quad * 8]);
            #pragma unroll
            for (int c = 0; c < 4; ++c) {
                bf16x8 vf = *reinterpret_cast<const bf16x8*>(&Vs[c * 16 + l16][s * 32 + quad * 8]);
                o[c] = __builtin_amdgcn_mfma_f32_16x16x32_bf16(pf, vf, o[c], 0, 0, 0);
            }
            ol = __builtin_amdgcn_mfma_f32_16x16x32_bf16(pf, ones, ol, 0, 0, 0);
        }
    }

    // ---- epilogue: normalize and write Y [B,T,C] bf16 ----
    #pragma unroll
    for (int r = 0; r < 4; ++r) {
        const int i = crow + r;
        const float invl = 1.0f / ol[r];
        #pragma unroll
        for (int c = 0; c < 4; ++c)
            Y[((size_t)b * T_ + i) * C_ + h * D_ + c * 16 + l16] = f2b(o[c][r] * invl);
    }
}

// ---------------------------------------------------------------------------
extern "C" void kernel_launch(void* const* d_in, const int* in_sizes, int n_in,
                              void* d_out, int out_size, void* d_ws, size_t ws_size,
                              hipStream_t stream)
{
    const float* x   = (const float*)d_in[0];
    const float* Wq  = (const float*)d_in[1];
    const float* bq  = (const float*)d_in[2];
    const float* Wk  = (const float*)d_in[3];
    const float* bk  = (const float*)d_in[4];
    const float* Wv  = (const float*)d_in[5];
    const float* bv  = (const float*)d_in[6];
    const float* Wp  = (const float*)d_in[7];
    const float* bp  = (const float*)d_in[8];
    const float* tbl = (const float*)d_in[9];
    float* out = (float*)d_out;

    const size_t n1 = (size_t)B_ * H_ * T_ * D_;       // 4,194,304
    const size_t nW = (size_t)C_ * C_;                 // 1,048,576
    unsigned short* xb  = (unsigned short*)d_ws;       // 8 MB
    unsigned short* Wqt = xb + (size_t)M_ * K_;        // 2 MB each
    unsigned short* Wkt = Wqt + nW;
    unsigned short* Wvt = Wkt + nW;
    unsigned short* Wpt = Wvt + nW;
    unsigned short* Qb  = Wpt + nW;                    // 8 MB each
    unsigned short* Kb  = Qb + n1;
    unsigned short* Vtb = Kb + n1;                     // V^T, written by gemm_qkv
    unsigned short* Yb  = Vtb + n1;
    float* dtab = (float*)(Yb + n1);                   // 128 KB
    float2* trig = (float2*)(dtab + H_ * T_);          // 512 KB (~48.6 MB total)

    const dim3 blk(256);

    convert_x<<<(M_ * K_) / (256 * 8), blk, 0, stream>>>(x, xb);
    convert_w<<<dim3(16, 16, 4), blk, 0, stream>>>(Wq, Wk, Wv, Wp, Wqt, Wkt, Wvt, Wpt);
    build_tabs<<<(T_ * 32) / 256, blk, 0, stream>>>(tbl, dtab, trig);

    gemm_qkv<<<dim3(C_ / 128, M_ / 128, 3), blk, 0, stream>>>(
        xb, Wqt, Wkt, Wvt, bq, bk, bv, trig, Qb, Kb, Vtb);

    flash_attn<<<dim3(32, B_ * H_), blk, 0, stream>>>(Qb, Kb, Vtb, dtab, Yb);

    gemm_proj<<<dim3(C_ / 128, M_ / 128), blk, 0, stream>>>(Yb, Wpt, bp, out);
}